// Round 15
// baseline (75.003 us; speedup 1.0000x reference)
//
#include <hip/hip_runtime.h>
#include <hip/hip_bf16.h>

#define D_ 64
#define HW_ 4096
#define K_ 1024
#define NPTS_ 65536
#define QOUT_ 4194304      // B*D*H*W, offset of idx region in d_out
#define DELTA 0.006f       // ambiguity margin; worst-case bf16-split diff ~2e-3
#define INF_ 3.4e38f

typedef short bf16x8 __attribute__((ext_vector_type(8)));
typedef float f32x4 __attribute__((ext_vector_type(4)));

// ---- pack kernel: cnorm + bf16 hi/lo split of (-2*cb) in MFMA-fragment order ----
// P layout (shorts): [g(64)][frag(4)][lane(64)][8]
//   code j = g*16 + (l&15), dims d = (frag>>1)*32 + (l>>4)*8 + i, lvl = frag&1
__global__ __launch_bounds__(256) void vq_pack(const float* __restrict__ cb,
                                               float* __restrict__ cnorm,
                                               short* __restrict__ P) {
    const int t = blockIdx.x * 256 + threadIdx.x;   // 0..4095
    const int gch = t >> 6, l = t & 63;
    const int j  = gch * 16 + (l & 15);
    const int dg = l >> 4;
#pragma unroll
    for (int s = 0; s < 2; ++s) {
        const float* src = cb + j * D_ + s * 32 + dg * 8;
        short hb[8], lb[8];
#pragma unroll
        for (int i = 0; i < 8; ++i) {
            const float v = -2.f * src[i];
            __hip_bfloat16 h = __float2bfloat16(v);
            hb[i] = *(const short*)&h;
            const float r = v - __bfloat162float(h);
            __hip_bfloat16 lo = __float2bfloat16(r);
            lb[i] = *(const short*)&lo;
        }
        // frag index: s*2 + lvl  (bh0,bl0 = dims 0..31; bh1,bl1 = dims 32..63)
        short* dh = P + ((size_t)(gch * 4 + s * 2 + 0) * 64 + l) * 8;
        short* dl = P + ((size_t)(gch * 4 + s * 2 + 1) * 64 + l) * 8;
#pragma unroll
        for (int i = 0; i < 8; ++i) { dh[i] = hb[i]; dl[i] = lb[i]; }
    }
    if (t < K_) {
        const float4* r = (const float4*)(cb + (size_t)t * D_);
        float s0 = 0.f, s1 = 0.f, s2 = 0.f, s3 = 0.f;
#pragma unroll
        for (int i = 0; i < 16; ++i) {
            float4 v = r[i];
            s0 = fmaf(v.x, v.x, s0); s1 = fmaf(v.y, v.y, s1);
            s2 = fmaf(v.z, v.z, s2); s3 = fmaf(v.w, v.w, s3);
        }
        cnorm[t] = (s0 + s1) + (s2 + s3);
    }
}

// ---- fused main: BARRIER-FREE global-B streaming MFMA argmin + epilogue ----
// 512 blocks x 256 thr (4 waves). Wave owns 32 pts (two 16x16 A-tiles) and
// streams ALL 1024 codes: B-fragments read directly from packed P (L2-resident
// 256 KB) via global_load_dwordx4 -- no LDS staging, no K-loop barriers, no
// merge. 2 waves/SIMD -> VGPR budget 256: #pragma unroll 8 gives the
// scheduler an 8-group load-hoisting window (deep ILP replaces TLP).
// Spill tripwire: FETCH/WRITE ballooning past ~25 MB.
__global__ __launch_bounds__(256, 2) void vq_main(const float* __restrict__ x,
                                                  const float* __restrict__ cb,
                                                  const float* __restrict__ cnorm_g,
                                                  const short* __restrict__ P,
                                                  float* __restrict__ out) {
    __shared__ float tile[64 * 69];    // 17.7 KB transpose staging (stride 69:
                                       // Phase-A writes 2-way = free)
    __shared__ int res_idx[128];
    __shared__ int flist[128];
    __shared__ int fcnt;

    const int tid  = threadIdx.x;
    const int lane = tid & 63;
    const int wid  = tid >> 6;        // 0..3 = 32-pt group
    const int pg   = blockIdx.x;      // 0..511
    const int bb   = pg >> 5;
    const int hw0  = (pg & 31) << 7;  // 128 pts per block

    if (tid == 0) fcnt = 0;

    // load + split x fragments: lane holds point (l&15), dims (l>>4)*8..+7
    bf16x8 ah[2][2], al[2][2];
    {
        const float* xb = x + (size_t)bb * (D_ * HW_) + hw0;
#pragma unroll
        for (int t = 0; t < 2; ++t) {
            const int p_l = wid * 32 + t * 16 + (lane & 15);
#pragma unroll
            for (int s = 0; s < 2; ++s) {
                const int d0 = s * 32 + (lane >> 4) * 8;
#pragma unroll
                for (int i = 0; i < 8; ++i) {
                    const float v = xb[(size_t)(d0 + i) * HW_ + p_l];
                    __hip_bfloat16 h = __float2bfloat16(v);
                    ah[t][s][i] = *(const short*)&h;
                    const float r = v - __bfloat162float(h);
                    __hip_bfloat16 lo = __float2bfloat16(r);
                    al[t][s][i] = *(const short*)&lo;
                }
            }
        }
    }
    __syncthreads();   // fcnt init visible (also x loads done; no other sync)

    float m1[8], m2[8];
    int   i1[8];
#pragma unroll
    for (int q = 0; q < 8; ++q) { m1[q] = INF_; m2[q] = INF_; i1[q] = 0; }

    const bf16x8* gp = (const bf16x8*)P;
#pragma unroll 8
    for (int g = 0; g < 64; ++g) {
        const int kc = g * 16 + (lane & 15);
        const float cn = cnorm_g[kc];                 // 4 KB, L1-resident
        bf16x8 bh0 = gp[(g * 4 + 0) * 64 + lane];     // 1 KB coalesced, L2-hit
        bf16x8 bl0 = gp[(g * 4 + 1) * 64 + lane];
        bf16x8 bh1 = gp[(g * 4 + 2) * 64 + lane];
        bf16x8 bl1 = gp[(g * 4 + 3) * 64 + lane];
        f32x4 a0a = {0.f, 0.f, 0.f, 0.f};   // tile0, dims 0-31 (3-deep chain)
        f32x4 a0b = {0.f, 0.f, 0.f, 0.f};   // tile0, dims 32-63
        f32x4 a1a = {0.f, 0.f, 0.f, 0.f};   // tile1, dims 0-31
        f32x4 a1b = {0.f, 0.f, 0.f, 0.f};   // tile1, dims 32-63
        a0a = __builtin_amdgcn_mfma_f32_16x16x32_bf16(ah[0][0], bh0, a0a, 0, 0, 0);
        a1a = __builtin_amdgcn_mfma_f32_16x16x32_bf16(ah[1][0], bh0, a1a, 0, 0, 0);
        a0b = __builtin_amdgcn_mfma_f32_16x16x32_bf16(ah[0][1], bh1, a0b, 0, 0, 0);
        a1b = __builtin_amdgcn_mfma_f32_16x16x32_bf16(ah[1][1], bh1, a1b, 0, 0, 0);
        a0a = __builtin_amdgcn_mfma_f32_16x16x32_bf16(al[0][0], bh0, a0a, 0, 0, 0);
        a1a = __builtin_amdgcn_mfma_f32_16x16x32_bf16(al[1][0], bh0, a1a, 0, 0, 0);
        a0b = __builtin_amdgcn_mfma_f32_16x16x32_bf16(al[0][1], bh1, a0b, 0, 0, 0);
        a1b = __builtin_amdgcn_mfma_f32_16x16x32_bf16(al[1][1], bh1, a1b, 0, 0, 0);
        a0a = __builtin_amdgcn_mfma_f32_16x16x32_bf16(ah[0][0], bl0, a0a, 0, 0, 0);
        a1a = __builtin_amdgcn_mfma_f32_16x16x32_bf16(ah[1][0], bl0, a1a, 0, 0, 0);
        a0b = __builtin_amdgcn_mfma_f32_16x16x32_bf16(ah[0][1], bl1, a0b, 0, 0, 0);
        a1b = __builtin_amdgcn_mfma_f32_16x16x32_bf16(ah[1][1], bl1, a1b, 0, 0, 0);
#pragma unroll
        for (int t = 0; t < 2; ++t)
#pragma unroll
            for (int r = 0; r < 4; ++r) {
                const int q = t * 4 + r;
                const float d2 = cn + ((t == 0) ? (a0a[r] + a0b[r])
                                                : (a1a[r] + a1b[r]));
                const bool lt = d2 < m1[q];
                m2[q] = fminf(m2[q], fmaxf(m1[q], d2));  // min(m2, loser)
                m1[q] = fminf(m1[q], d2);
                i1[q] = lt ? kc : i1[q];
            }
    }

    // cross-lane (m1,i1,m2) reduce over the 16 lanes sharing (lane>>4);
    // result is FINAL (wave covered all K) -> flag + store directly.
#pragma unroll
    for (int q = 0; q < 8; ++q) {
        float a1 = m1[q], a2 = m2[q];
        int   ai = i1[q];
#pragma unroll
        for (int m = 1; m < 16; m <<= 1) {
            const float o1 = __shfl_xor(a1, m);
            const int   oi = __shfl_xor(ai, m);
            const float o2 = __shfl_xor(a2, m);
            const float nm2 = fminf(fminf(a2, o2), fmaxf(a1, o1));
            if (o1 < a1 || (o1 == a1 && oi < ai)) { a1 = o1; ai = oi; }
            a2 = nm2;
        }
        if ((lane & 15) == 0) {
            const int t = q >> 2, r = q & 3;
            const int pt = wid * 32 + t * 16 + 4 * (lane >> 4) + r;
            res_idx[pt] = ai;
            if (a2 - a1 <= DELTA) { const int p = atomicAdd(&fcnt, 1); flist[p] = pt; }
        }
    }
    __syncthreads();

    // exact fp32 rescan for ambiguous points (expected ~0.1/block)
    const int nf = fcnt;
    for (int i = wid; i < nf; i += 4) {
        const int pt = flist[i];
        const float* xr = x + (size_t)bb * (D_ * HW_) + hw0 + pt;
        float xv[D_];
#pragma unroll
        for (int d = 0; d < D_; ++d) xv[d] = xr[(size_t)d * HW_];   // wave-uniform
        float b1 = INF_; int bi = 0;
        for (int cc = 0; cc < 16; ++cc) {
            const int row = lane * 16 + cc;
            const float4* cr = (const float4*)(cb + (size_t)row * D_);
            float a0 = 0.f, a1 = 0.f, a2 = 0.f, a3 = 0.f;
#pragma unroll
            for (int g = 0; g < 16; ++g) {
                const float4 cf = cr[g];
                a0 = fmaf(xv[4 * g + 0], cf.x, a0);
                a1 = fmaf(xv[4 * g + 1], cf.y, a1);
                a2 = fmaf(xv[4 * g + 2], cf.z, a2);
                a3 = fmaf(xv[4 * g + 3], cf.w, a3);
            }
            const float dot = (a0 + a1) + (a2 + a3);
            const float d2 = fmaf(-2.f, dot, cnorm_g[row]);
            if (d2 < b1) { b1 = d2; bi = row; }
        }
#pragma unroll
        for (int m = 1; m < 64; m <<= 1) {
            const float o1 = __shfl_xor(b1, m);
            const int   oi = __shfl_xor(bi, m);
            if (o1 < b1 || (o1 == b1 && oi < bi)) { b1 = o1; bi = oi; }
        }
        if (lane == 0) res_idx[pt] = bi;
    }
    __syncthreads();

    // idx output (float; exact for values <= 1023)
    if (tid < 128) out[(size_t)QOUT_ + pg * 128 + tid] = (float)res_idx[tid];

    // Phase A: gather winning rows (16 lanes x 16 B = full 256 B row each),
    // write transposed into [d][pt] tile. Stride 69 -> write conflicts 2-way (free).
#pragma unroll
    for (int pass = 0; pass < 8; ++pass) {
        const int pt = pass * 16 + (tid >> 4);
        const int dq = tid & 15;
        const float4 v = *(const float4*)(cb + (size_t)res_idx[pt] * D_ + dq * 4);
        tile[(dq * 4 + 0) * 69 + pt] = v.x;
        tile[(dq * 4 + 1) * 69 + pt] = v.y;
        tile[(dq * 4 + 2) * 69 + pt] = v.z;
        tile[(dq * 4 + 3) * 69 + pt] = v.w;
    }
    __syncthreads();

    // Phase B: float4 stores; per d, 128 pts x 4 B = 512 B contiguous
    float* ob = out + (size_t)bb * (D_ * HW_) + hw0;
#pragma unroll
    for (int it = 0; it < 8; ++it) {
        const int e = it * 256 + tid;   // 0..2047
        const int d = e >> 5;
        const int g = e & 31;
        const float4 q = *(const float4*)&tile[d * 69 + g * 4];
        *(float4*)(ob + (size_t)d * HW_ + g * 4) = q;
    }
}

extern "C" void kernel_launch(void* const* d_in, const int* in_sizes, int n_in,
                              void* d_out, int out_size, void* d_ws, size_t ws_size,
                              hipStream_t stream) {
    const float* x  = (const float*)d_in[0];   // (16, 64, 64, 64)
    const float* cb = (const float*)d_in[1];   // (1024, 64)
    float* out   = (float*)d_out;
    float* cnorm = (float*)d_ws;                       // 4 KB
    short* P     = (short*)((char*)d_ws + 4096);       // 256 KB packed bf16 codebook

    vq_pack<<<16, 256, 0, stream>>>(cb, cnorm, P);
    vq_main<<<NPTS_ / 128, 256, 0, stream>>>(x, cb, cnorm, P, out);
}

// Round 16
// 62.148 us; speedup vs baseline: 1.2068x; 1.2068x over previous
//
#include <hip/hip_runtime.h>
#include <hip/hip_bf16.h>

#define D_ 64
#define HW_ 4096
#define K_ 1024
#define NPTS_ 65536
#define QOUT_ 4194304      // B*D*H*W, offset of idx region in d_out
#define DELTA 0.006f       // ambiguity margin; worst-case bf16-split diff ~2e-3
#define INF_ 3.4e38f
#define NCH 16             // chunks of 64 codes

typedef short bf16x8 __attribute__((ext_vector_type(8)));
typedef float f32x4 __attribute__((ext_vector_type(4)));

__device__ __forceinline__ void gload_lds16(const float* g, float* l) {
    __builtin_amdgcn_global_load_lds((const __attribute__((address_space(1))) void*)g,
                                     (__attribute__((address_space(3))) void*)l, 16, 0, 0);
}
__device__ __forceinline__ void gload_lds4(const float* g, float* l) {
    __builtin_amdgcn_global_load_lds((const __attribute__((address_space(1))) void*)g,
                                     (__attribute__((address_space(3))) void*)l, 4, 0, 0);
}

// ---- pack kernel: cnorm + bf16 hi/lo split of (-2*cb) in MFMA-fragment order ----
// P layout (shorts): [gch(64)][frag(4)][lane(64)][8]
//   code j = gch*16 + (l&15), dims d = (frag>>1)*32 + (l>>4)*8 + i, lvl = frag&1
__global__ __launch_bounds__(256) void vq_pack(const float* __restrict__ cb,
                                               float* __restrict__ cnorm,
                                               short* __restrict__ P) {
    const int t = blockIdx.x * 256 + threadIdx.x;   // 0..4095
    const int gch = t >> 6, l = t & 63;
    const int j  = gch * 16 + (l & 15);
    const int dg = l >> 4;
#pragma unroll
    for (int s = 0; s < 2; ++s) {
        const float* src = cb + j * D_ + s * 32 + dg * 8;
        short hb[8], lb[8];
#pragma unroll
        for (int i = 0; i < 8; ++i) {
            const float v = -2.f * src[i];
            __hip_bfloat16 h = __float2bfloat16(v);
            hb[i] = *(const short*)&h;
            const float r = v - __bfloat162float(h);
            __hip_bfloat16 lo = __float2bfloat16(r);
            lb[i] = *(const short*)&lo;
        }
        short* dh = P + ((size_t)(gch * 4 + s * 2 + 0) * 64 + l) * 8;
        short* dl = P + ((size_t)(gch * 4 + s * 2 + 1) * 64 + l) * 8;
#pragma unroll
        for (int i = 0; i < 8; ++i) { dh[i] = hb[i]; dl[i] = lb[i]; }
    }
    if (t < K_) {
        const float4* r = (const float4*)(cb + (size_t)t * D_);
        float s0 = 0.f, s1 = 0.f, s2 = 0.f, s3 = 0.f;
#pragma unroll
        for (int i = 0; i < 16; ++i) {
            float4 v = r[i];
            s0 = fmaf(v.x, v.x, s0); s1 = fmaf(v.y, v.y, s1);
            s2 = fmaf(v.z, v.z, s2); s3 = fmaf(v.w, v.w, s3);
        }
        cnorm[t] = (s0 + s1) + (s2 + s3);
    }
}

// stage one 16 KB chunk: 4 wave-rounds x 1 KB (wave-uniform dst, linear)
__device__ __forceinline__ void stage_chunk(const float* src, float* dst,
                                            int wid, int lane) {
#pragma unroll
    for (int r = 0; r < 4; ++r)
        gload_lds16(src + (wid * 4 + r) * 256 + lane * 4,
                    dst + (wid * 4 + r) * 256);
}

// ---- fused main: 3-deep counted-vmcnt pipelined MFMA argmin + epilogue ----
// 512 blocks x 256 thr (4 waves x 32 pts = 128 pts). Every wave scans all
// 1024 codes (no merge). 16 chunks x 64 codes, LDS triple-buffered (48 KB):
// stage c+2 at iter top, compute c, s_waitcnt vmcnt(4) (c+1 stays in flight)
// + raw s_barrier -- NO vmcnt(0) drain in the loop (the R12/R14 serializer).
// Tripwires: absmax != 0 -> pipeline race; WRITE >> 17 MB -> spill.
__global__ __launch_bounds__(256, 2) void vq_main(const float* __restrict__ x,
                                                  const float* __restrict__ cb,
                                                  const float* __restrict__ cnorm_g,
                                                  const short* __restrict__ P,
                                                  float* __restrict__ out) {
    __shared__ short cbuf[3][8192];    // 3 x 16 KB code buffers
    __shared__ float cnt[K_];          // 4 KB
    __shared__ int res_idx[128];
    __shared__ int flist[128];
    __shared__ int fcnt;

    const int tid  = threadIdx.x;
    const int lane = tid & 63;
    const int wid  = tid >> 6;        // 0..3 = 32-pt group
    const int pg   = blockIdx.x;      // 0..511
    const int bb   = pg >> 5;
    const int hw0  = (pg & 31) << 7;  // 128 pts per block

    if (tid == 0) fcnt = 0;

    const float* Pf = (const float*)P;
    float* buf0 = (float*)cbuf[0];
    float* buf1 = (float*)cbuf[1];
    float* buf2 = (float*)cbuf[2];

    // prologue: issue cnt + chunk0 + chunk1 (12 loads/wave outstanding)
#pragma unroll
    for (int r = 0; r < 4; ++r)
        gload_lds4(cnorm_g + (wid * 4 + r) * 64 + lane, cnt + (wid * 4 + r) * 64);
    stage_chunk(Pf, buf0, wid, lane);
    stage_chunk(Pf + 4096, buf1, wid, lane);

    // x load + split (long; loads above keep flying underneath)
    bf16x8 ah[2][2], al[2][2];
    {
        const float* xb = x + (size_t)bb * (D_ * HW_) + hw0;
#pragma unroll
        for (int t = 0; t < 2; ++t) {
            const int p_l = wid * 32 + t * 16 + (lane & 15);
#pragma unroll
            for (int s = 0; s < 2; ++s) {
                const int d0 = s * 32 + (lane >> 4) * 8;
#pragma unroll
                for (int i = 0; i < 8; ++i) {
                    const float v = xb[(size_t)(d0 + i) * HW_ + p_l];
                    __hip_bfloat16 h = __float2bfloat16(v);
                    ah[t][s][i] = *(const short*)&h;
                    const float r = v - __bfloat162float(h);
                    __hip_bfloat16 lo = __float2bfloat16(r);
                    al[t][s][i] = *(const short*)&lo;
                }
            }
        }
    }
    asm volatile("s_waitcnt vmcnt(4)" ::: "memory");   // cnt+chunk0 done; chunk1 may fly
    __builtin_amdgcn_s_barrier();
    asm volatile("" ::: "memory");

    float m1[8], m2[8];
    int   i1[8];
#pragma unroll
    for (int q = 0; q < 8; ++q) { m1[q] = INF_; m2[q] = INF_; i1[q] = 0; }

    float* bcur = buf0;   // chunk c
    float* bnxt = buf1;   // chunk c+1 (in flight allowed)
    float* bstg = buf2;   // staging dest for chunk c+2
#pragma unroll 1
    for (int c = 0; c < NCH; ++c) {
        if (c + 2 < NCH) stage_chunk(Pf + (size_t)(c + 2) * 4096, bstg, wid, lane);

        const bf16x8* fr = (const bf16x8*)bcur;
#pragma unroll
        for (int gl = 0; gl < 4; ++gl) {
            const int kc = c * 64 + gl * 16 + (lane & 15);
            const float cn = cnt[kc];
            bf16x8 bh0 = fr[(gl * 4 + 0) * 64 + lane];
            bf16x8 bl0 = fr[(gl * 4 + 1) * 64 + lane];
            bf16x8 bh1 = fr[(gl * 4 + 2) * 64 + lane];
            bf16x8 bl1 = fr[(gl * 4 + 3) * 64 + lane];
            f32x4 a0a = {0.f, 0.f, 0.f, 0.f};   // tile0, dims 0-31 (3-deep)
            f32x4 a0b = {0.f, 0.f, 0.f, 0.f};   // tile0, dims 32-63
            f32x4 a1a = {0.f, 0.f, 0.f, 0.f};   // tile1, dims 0-31
            f32x4 a1b = {0.f, 0.f, 0.f, 0.f};   // tile1, dims 32-63
            a0a = __builtin_amdgcn_mfma_f32_16x16x32_bf16(ah[0][0], bh0, a0a, 0, 0, 0);
            a1a = __builtin_amdgcn_mfma_f32_16x16x32_bf16(ah[1][0], bh0, a1a, 0, 0, 0);
            a0b = __builtin_amdgcn_mfma_f32_16x16x32_bf16(ah[0][1], bh1, a0b, 0, 0, 0);
            a1b = __builtin_amdgcn_mfma_f32_16x16x32_bf16(ah[1][1], bh1, a1b, 0, 0, 0);
            a0a = __builtin_amdgcn_mfma_f32_16x16x32_bf16(al[0][0], bh0, a0a, 0, 0, 0);
            a1a = __builtin_amdgcn_mfma_f32_16x16x32_bf16(al[1][0], bh0, a1a, 0, 0, 0);
            a0b = __builtin_amdgcn_mfma_f32_16x16x32_bf16(al[0][1], bh1, a0b, 0, 0, 0);
            a1b = __builtin_amdgcn_mfma_f32_16x16x32_bf16(al[1][1], bh1, a1b, 0, 0, 0);
            a0a = __builtin_amdgcn_mfma_f32_16x16x32_bf16(ah[0][0], bl0, a0a, 0, 0, 0);
            a1a = __builtin_amdgcn_mfma_f32_16x16x32_bf16(ah[1][0], bl0, a1a, 0, 0, 0);
            a0b = __builtin_amdgcn_mfma_f32_16x16x32_bf16(ah[0][1], bl1, a0b, 0, 0, 0);
            a1b = __builtin_amdgcn_mfma_f32_16x16x32_bf16(ah[1][1], bl1, a1b, 0, 0, 0);
#pragma unroll
            for (int t = 0; t < 2; ++t)
#pragma unroll
                for (int r = 0; r < 4; ++r) {
                    const int q = t * 4 + r;
                    const float d2 = cn + ((t == 0) ? (a0a[r] + a0b[r])
                                                    : (a1a[r] + a1b[r]));
                    const bool lt = d2 < m1[q];
                    m2[q] = fminf(m2[q], fmaxf(m1[q], d2));
                    m1[q] = fminf(m1[q], d2);
                    i1[q] = lt ? kc : i1[q];
                }
        }

        // c+1's loads must land before next iter; c+2's (4) may stay in flight
        if (c + 2 < NCH) asm volatile("s_waitcnt vmcnt(4)" ::: "memory");
        else             asm volatile("s_waitcnt vmcnt(0)" ::: "memory");
        __builtin_amdgcn_s_barrier();
        asm volatile("" ::: "memory");

        float* t0 = bcur; bcur = bnxt; bnxt = bstg; bstg = t0;   // rotate
    }

    // cross-lane (m1,i1,m2) reduce over the 16 lanes sharing (lane>>4);
    // wave covered all K -> result final.
#pragma unroll
    for (int q = 0; q < 8; ++q) {
        float a1 = m1[q], a2 = m2[q];
        int   ai = i1[q];
#pragma unroll
        for (int m = 1; m < 16; m <<= 1) {
            const float o1 = __shfl_xor(a1, m);
            const int   oi = __shfl_xor(ai, m);
            const float o2 = __shfl_xor(a2, m);
            const float nm2 = fminf(fminf(a2, o2), fmaxf(a1, o1));
            if (o1 < a1 || (o1 == a1 && oi < ai)) { a1 = o1; ai = oi; }
            a2 = nm2;
        }
        if ((lane & 15) == 0) {
            const int t = q >> 2, r = q & 3;
            const int pt = wid * 32 + t * 16 + 4 * (lane >> 4) + r;
            res_idx[pt] = ai;
            if (a2 - a1 <= DELTA) { const int p = atomicAdd(&fcnt, 1); flist[p] = pt; }
        }
    }
    __syncthreads();

    // exact fp32 rescan for ambiguous points (expected ~0.1/block)
    const int nf = fcnt;
    for (int i = wid; i < nf; i += 4) {
        const int pt = flist[i];
        const float* xr = x + (size_t)bb * (D_ * HW_) + hw0 + pt;
        float xv[D_];
#pragma unroll
        for (int d = 0; d < D_; ++d) xv[d] = xr[(size_t)d * HW_];   // wave-uniform
        float b1 = INF_; int bi = 0;
        for (int cc = 0; cc < 16; ++cc) {
            const int row = lane * 16 + cc;
            const float4* cr = (const float4*)(cb + (size_t)row * D_);
            float a0 = 0.f, a1 = 0.f, a2 = 0.f, a3 = 0.f;
#pragma unroll
            for (int g = 0; g < 16; ++g) {
                const float4 cf = cr[g];
                a0 = fmaf(xv[4 * g + 0], cf.x, a0);
                a1 = fmaf(xv[4 * g + 1], cf.y, a1);
                a2 = fmaf(xv[4 * g + 2], cf.z, a2);
                a3 = fmaf(xv[4 * g + 3], cf.w, a3);
            }
            const float dot = (a0 + a1) + (a2 + a3);
            const float d2 = fmaf(-2.f, dot, cnt[row]);
            if (d2 < b1) { b1 = d2; bi = row; }
        }
#pragma unroll
        for (int m = 1; m < 64; m <<= 1) {
            const float o1 = __shfl_xor(b1, m);
            const int   oi = __shfl_xor(bi, m);
            if (o1 < b1 || (o1 == b1 && oi < bi)) { b1 = o1; bi = oi; }
        }
        if (lane == 0) res_idx[pt] = bi;
    }
    __syncthreads();

    // idx output (float; exact for values <= 1023)
    if (tid < 128) out[(size_t)QOUT_ + pg * 128 + tid] = (float)res_idx[tid];

    // Phase A: gather winning rows (16 lanes x 16 B = full 256 B row each),
    // write into [pt][65] tile (aliases cbuf, 128*65*4 = 33.3 KB <= 48 KB).
    // Write banks: pt + 4*dq + j -> 2-way max (free).
    float* tile = (float*)cbuf;
#pragma unroll
    for (int pass = 0; pass < 8; ++pass) {
        const int pt = pass * 16 + (tid >> 4);
        const int dq = tid & 15;
        const float4 v = *(const float4*)(cb + (size_t)res_idx[pt] * D_ + dq * 4);
        tile[pt * 65 + dq * 4 + 0] = v.x;
        tile[pt * 65 + dq * 4 + 1] = v.y;
        tile[pt * 65 + dq * 4 + 2] = v.z;
        tile[pt * 65 + dq * 4 + 3] = v.w;
    }
    __syncthreads();

    // Phase B: per thread, 4 scalar tile reads -> one float4 store (512 B
    // contiguous per 32-lane group per d)
    float* ob = out + (size_t)bb * (D_ * HW_) + hw0;
#pragma unroll
    for (int it = 0; it < 8; ++it) {
        const int e = it * 256 + tid;   // 0..2047
        const int d = e >> 5;           // 0..63
        const int g = e & 31;           // float4 group within 128 pts
        float4 q;
        q.x = tile[(g * 4 + 0) * 65 + d];
        q.y = tile[(g * 4 + 1) * 65 + d];
        q.z = tile[(g * 4 + 2) * 65 + d];
        q.w = tile[(g * 4 + 3) * 65 + d];
        *(float4*)(ob + (size_t)d * HW_ + g * 4) = q;
    }
}

extern "C" void kernel_launch(void* const* d_in, const int* in_sizes, int n_in,
                              void* d_out, int out_size, void* d_ws, size_t ws_size,
                              hipStream_t stream) {
    const float* x  = (const float*)d_in[0];   // (16, 64, 64, 64)
    const float* cb = (const float*)d_in[1];   // (1024, 64)
    float* out   = (float*)d_out;
    float* cnorm = (float*)d_ws;                       // 4 KB
    short* P     = (short*)((char*)d_ws + 4096);       // 256 KB packed bf16 codebook

    vq_pack<<<16, 256, 0, stream>>>(cb, cnorm, P);
    vq_main<<<NPTS_ / 128, 256, 0, stream>>>(x, cb, cnorm, P, out);
}